// Round 10
// baseline (162.122 us; speedup 1.0000x reference)
//
#include <hip/hip_runtime.h>

// out[b,h] = sum_{i,j} cb[h, i*64+j] * in1[b,i] * in2[b,j]
// B = 4096, dim1 = dim2 = 64, H = 4096.
//
// Round-9: MFMA reformulation. For each slot pair s = (s1,s2) (16 total):
//   out[b, R_s[r]] = sum_e outer_s[b,e] * W[r,e],  r,e in [0,256)
// where e = (combo c, i, j) packed (eoff prefix of n1*n2), outer_s[b,e] =
// in1[b, kBase[l1]+s1*n1+i] * in2[b, kBase[l2]+s2*n2+j], W is the shared
// block-diagonal 256x256 Wigner matrix (slot-independent; sum n1n2 = 256
// exactly -> K=256, N=256 tile perfectly). Dense f16 MFMA 16x16x32.
// Every block does identical work -> perfectly balanced.
//
// prep: WT[r][e] f16 (B-operand, n-major), R[s][r] u16 (output h scatter),
//       C12[s][e] u16 (packed input gather cols).
// main: grid (128 btiles x 16 slots), 256 thr / 4 waves, M=32 per block.
//   stage in1/in2 -> LDS; build A[m][e] f16 in LDS; 4 waves x 4 ntiles x
//   2 mtiles x 8 ksteps of mfma_f32_16x16x32_f16; scatter epilogue.

typedef _Float16 half8 __attribute__((ext_vector_type(8)));
typedef float f32x4 __attribute__((ext_vector_type(4)));

__constant__ int   kStart[7] = {0, 64, 496, 1376, 2496, 3360, 3888};
__constant__ int   kBase[4] = {0, 4, 16, 36};
__constant__ short kEoff[17] = {0,1,4,9,16,19,28,43,64,69,84,109,144,151,172,207,256};
// position of combo c = l1*4+l2 within the (stable-sorted) kVp list of l3
__constant__ signed char kVpPos[7][16] = {
  { 0,-1,-1,-1,-1, 1,-1,-1,-1,-1, 2,-1,-1,-1,-1, 3},   // l3=0: [0,5,10,15]
  {-1, 0,-1,-1, 1, 2, 3,-1,-1, 4, 5, 6,-1,-1, 7, 8},   // l3=1: [1,4,5,6,9,10,11,14,15]
  {-1,-1, 0,-1,-1, 1, 2, 3, 4, 5, 6, 7,-1, 8, 9,10},   // l3=2: [2,5,6,7,8,9,10,11,13,14,15]
  {-1,-1,-1, 0,-1,-1, 1, 2,-1, 3, 4, 5, 6, 7, 8, 9},   // l3=3: [3,6,7,9,10,11,12,13,14,15]
  {-1,-1,-1,-1,-1,-1,-1, 0,-1,-1, 1, 2,-1, 3, 4, 5},   // l3=4: [7,10,11,13,14,15]
  {-1,-1,-1,-1,-1,-1,-1,-1,-1,-1,-1, 0,-1,-1, 1, 2},   // l3=5: [11,14,15]
  {-1,-1,-1,-1,-1,-1,-1,-1,-1,-1,-1,-1,-1,-1,-1, 0}    // l3=6: [15]
};

__device__ __forceinline__ int find_c(int x) {
  int c = 15;
  while (x < (int)kEoff[c]) --c;
  return c;
}

// grid 256 x 256 thr: r = blockIdx.x, e = threadIdx.x
__global__ __launch_bounds__(256) void prep_kernel(
    const float* __restrict__ cb, _Float16* __restrict__ WT,
    unsigned short* __restrict__ R, unsigned short* __restrict__ C12) {
  int r = blockIdx.x;
  int e = threadIdx.x;
  // decode e -> (ce, qi, rj)
  int ce = find_c(e);
  int el = e - (int)kEoff[ce];
  int l1e = ce >> 2, l2e = ce & 3;
  int n1e = 2 * l1e + 1, n2e = 2 * l2e + 1;
  int qi = el / n2e, rj = el - qi * n2e;
  // decode r -> (cr, l3, k)
  int cr = find_c(r);
  int rl = r - (int)kEoff[cr];
  int l1r = cr >> 2, l2r = cr & 3;
  int l3 = l1r - l2r; if (l3 < 0) l3 = -l3;
  while (rl >= 2 * l3 + 1) { rl -= 2 * l3 + 1; ++l3; }
  float val = 0.f;
  if (ce == cr) {
    int h = kStart[l3] + (int)kVpPos[l3][cr] * 16 * (2 * l3 + 1) + rl;  // slot 0
    val = cb[(size_t)h * 4096 + (kBase[l1e] + qi) * 64 + (kBase[l2e] + rj)];
  }
  WT[r * 256 + e] = (_Float16)val;
  if (r < 16) {
    int s = r, s1 = s >> 2, s2 = s & 3;
    int c1 = kBase[l1e] + s1 * n1e + qi;
    int c2 = kBase[l2e] + s2 * n2e + rj;
    C12[s * 256 + e] = (unsigned short)(c1 | (c2 << 8));
    // decode e as a ROW index for the scatter table
    int xl = el, l3x = l1e - l2e; if (l3x < 0) l3x = -l3x;
    while (xl >= 2 * l3x + 1) { xl -= 2 * l3x + 1; ++l3x; }
    R[s * 256 + e] = (unsigned short)(
        kStart[l3x] + ((int)kVpPos[l3x][ce] * 16 + s) * (2 * l3x + 1) + xl);
  }
}

#define S1S 66    // s1/s2 f32 row stride
#define APH 264   // A row stride in halfs (256 + 8 pad -> 528B, bank-rotating)

__global__ __launch_bounds__(256) void tp_kernel(
    const float* __restrict__ in1, const float* __restrict__ in2,
    const _Float16* __restrict__ WT, const unsigned short* __restrict__ R,
    const unsigned short* __restrict__ C12, float* __restrict__ out) {
  __shared__ float s1[32 * S1S];
  __shared__ float s2[32 * S1S];
  __shared__ _Float16 A[32 * APH];   // [m][e] f16

  const int tid = threadIdx.x;
  const int b0 = blockIdx.x << 5;    // batch tile (32)
  const int s  = blockIdx.y;         // slot pair
  const int wv = tid >> 6, lane = tid & 63;
  const int quad = lane >> 4, l15 = lane & 15;

  // ---- stage in1/in2 tiles (32 x 64 f32 each), coalesced float4 ----
#pragma unroll
  for (int it = 0; it < 2; ++it) {
    int idx4 = it * 256 + tid;
    int m = idx4 >> 4, d0 = (idx4 & 15) << 2;
    *reinterpret_cast<float4*>(&s1[m * S1S + d0]) =
        *reinterpret_cast<const float4*>(&in1[(size_t)(b0 + m) * 64 + d0]);
    *reinterpret_cast<float4*>(&s2[m * S1S + d0]) =
        *reinterpret_cast<const float4*>(&in2[(size_t)(b0 + m) * 64 + d0]);
  }

  // this thread builds A[m][e0..e0+31]; fetch its gather cols (64B) now
  const int m  = tid >> 3;
  const int e0 = (tid & 7) << 5;
  uint4 cw[4];
  {
    const uint4* cp = reinterpret_cast<const uint4*>(C12 + s * 256 + e0);
    cw[0] = cp[0]; cw[1] = cp[1]; cw[2] = cp[2]; cw[3] = cp[3];
  }
  __syncthreads();

  // ---- A-build: outer products, f32 -> f16 ----
  const unsigned* cwu = reinterpret_cast<const unsigned*>(cw);
#pragma unroll
  for (int ee = 0; ee < 32; ee += 4) {
    union { _Float16 h[4]; uint2 u; } pk;
#pragma unroll
    for (int u = 0; u < 4; ++u) {
      unsigned w = cwu[(ee + u) >> 1];
      unsigned hw = ((ee + u) & 1) ? (w >> 16) : w;
      int c1 = hw & 255, c2 = (hw >> 8) & 255;
      pk.h[u] = (_Float16)(s1[m * S1S + c1] * s2[m * S1S + c2]);
    }
    *reinterpret_cast<uint2*>(&A[m * APH + e0 + ee]) = pk.u;  // ds_write_b64
  }
  __syncthreads();

  // ---- MFMA: wave wv owns ntiles 4wv..4wv+3; K = 256 (8 steps) ----
#pragma unroll 1
  for (int ntl = 0; ntl < 4; ++ntl) {
    int nt = (wv << 2) + ntl;
    int hh = (int)R[s * 256 + (nt << 4) + l15];      // output h for lane col
    half8 bf[8];
    const _Float16* wp = WT + (size_t)((nt << 4) + l15) * 256 + (quad << 3);
#pragma unroll
    for (int kt = 0; kt < 8; ++kt)
      bf[kt] = *reinterpret_cast<const half8*>(wp + (kt << 5));
#pragma unroll
    for (int mt = 0; mt < 2; ++mt) {
      const _Float16* ap = &A[((mt << 4) + l15) * APH + (quad << 3)];
      f32x4 acc = {0.f, 0.f, 0.f, 0.f};
#pragma unroll
      for (int kt = 0; kt < 8; ++kt) {
        half8 af = *reinterpret_cast<const half8*>(ap + (kt << 5));  // ds_read_b128
        acc = __builtin_amdgcn_mfma_f32_16x16x32_f16(af, bf[kt], acc, 0, 0, 0);
      }
      // D[m = quad*4+rr][n = l15] -> out[b0+mt*16+m][hh]
      float* op = out + (size_t)(b0 + (mt << 4) + (quad << 2)) * 4096 + hh;
#pragma unroll
      for (int rr = 0; rr < 4; ++rr) op[(size_t)rr * 4096] = acc[rr];
    }
  }
}

extern "C" void kernel_launch(void* const* d_in, const int* in_sizes, int n_in,
                              void* d_out, int out_size, void* d_ws, size_t ws_size,
                              hipStream_t stream) {
  const float* in1 = (const float*)d_in[0];
  const float* in2 = (const float*)d_in[1];
  const float* cb  = (const float*)d_in[2];
  float* out = (float*)d_out;
  _Float16* WT = (_Float16*)d_ws;                                  // 128 KB
  unsigned short* R   = (unsigned short*)((char*)d_ws + 131072);   // 8 KB
  unsigned short* C12 = (unsigned short*)((char*)d_ws + 139264);   // 8 KB
  (void)in_sizes; (void)n_in; (void)out_size; (void)ws_size;
  prep_kernel<<<256, 256, 0, stream>>>(cb, WT, R, C12);
  tp_kernel<<<dim3(128, 16), 256, 0, stream>>>(in1, in2, WT, R, C12, out);
}